// Round 13
// baseline (748.845 us; speedup 1.0000x reference)
//
#include <hip/hip_runtime.h>
#include <stdint.h>

#define TB     400
#define OUTROW 160000   // T * 2F

typedef _Float16 half2_t __attribute__((ext_vector_type(2)));
typedef __fp16   fp16v2  __attribute__((ext_vector_type(2)));
typedef uint16_t u16;
typedef uint32_t u32;

#if defined(__has_builtin)
#  if __has_builtin(__builtin_amdgcn_fdot2)
#    define HAVE_FDOT2 1
#  endif
#endif

__device__ __forceinline__ float sigf(float x){ return 1.0f/(1.0f+__expf(-x)); }
__device__ __forceinline__ float tanhf_(float x){ float e=__expf(2.0f*x); return 1.0f-2.0f/(e+1.0f); }
__device__ __forceinline__ u16 h16(float x){ _Float16 h=(_Float16)x; return __builtin_bit_cast(u16,h); }
__device__ __forceinline__ u32 pk2(float a, float b){ return (u32)h16(a) | ((u32)h16(b)<<16); }
__device__ __forceinline__ u32 pkrtz(float a, float b){
  fp16v2 v = __builtin_amdgcn_cvt_pkrtz(a,b);
  return __builtin_bit_cast(u32, v);
}
__device__ __forceinline__ float f16f(u16 u){ return (float)__builtin_bit_cast(_Float16,u); }
__device__ __forceinline__ float dot2f(u32 w, u32 x, float acc){
#ifdef HAVE_FDOT2
  return __builtin_amdgcn_fdot2(__builtin_bit_cast(half2_t,w), __builtin_bit_cast(half2_t,x), acc, false);
#else
  half2_t a = __builtin_bit_cast(half2_t,w), b = __builtin_bit_cast(half2_t,x);
  return acc + (float)a.x*(float)b.x + (float)a.y*(float)b.y;
#endif
}

// ---------- k_q: Q = P @ W_m (100x400 per dir), f16 k-pair packed, rows 100..103 = 0 ----
__global__ __launch_bounds__(512)
void k_q(const float* __restrict__ Wf, const float* __restrict__ Pf,
         const float* __restrict__ Wb, const float* __restrict__ Pb,
         u32* __restrict__ Qp)
{
  const int b = blockIdx.x, dir = b/52, j = b%52, tid = threadIdx.x;
  const float* W = dir?Wb:Wf; const float* P = dir?Pb:Pf;
  __shared__ float pr[2][200];
  for (int i=tid;i<400;i+=512){ int u=i/200,k=i%200; int hk=2*j+u;
    pr[u][k] = (hk<100)? P[(size_t)hk*200+k] : 0.f; }
  __syncthreads();
  if (tid<400){
    float a0=0.f,a1=0.f;
    for (int k=0;k<200;++k){ float w = W[(size_t)(100+k)*400+tid]; a0 += pr[0][k]*w; a1 += pr[1][k]*w; }
    Qp[(size_t)(dir*52+j)*400+tid] = pk2(a0,a1);
  }
}

// ---------- k_m0: M0W[dir][seq][c] = m0 @ W_m  (first-step recurrent term, f32) ----------
__global__ __launch_bounds__(512)
void k_m0(const float* __restrict__ m0f, const float* __restrict__ m0b,
          const float* __restrict__ Wf, const float* __restrict__ Wb,
          float* __restrict__ M0W)
{
  const int b = blockIdx.x, dir=b>>7, seq=b&127, tid=threadIdx.x;
  const float* m0 = dir?m0b:m0f; const float* W = dir?Wb:Wf;
  __shared__ float mr[200];
  if (tid<200) mr[tid] = m0[(size_t)seq*200+tid];
  __syncthreads();
  if (tid<400){
    float a=0.f;
    for (int k=0;k<200;++k) a += mr[k]*W[(size_t)(100+k)*400+tid];
    M0W[(size_t)b*400+tid] = a;
  }
}

// ---------- k_g2: G for BOTH dirs; x via uniform global float4 loads + in-reg pack ----
// grid 1024: block = seq*8 + t-octile (50 rows). Thread owns col c for dir0 AND dir1.
__global__ __launch_bounds__(512)
void k_g2(const float* __restrict__ z,
          const float* __restrict__ Wf, const float* __restrict__ bf,
          const float* __restrict__ Wb, const float* __restrict__ bb,
          const float* __restrict__ M0W, u16* __restrict__ Gh)
{
  const int b = blockIdx.x, seq = b>>3, t0 = (b&7)*50, tid = threadIdx.x;
  if (tid >= 400) return;
  u32 wc0[50], wc1[50];
  #pragma unroll
  for (int j=0;j<50;++j){
    wc0[j] = pk2(Wf[(size_t)(2*j)*400+tid], Wf[(size_t)(2*j+1)*400+tid]);
    wc1[j] = pk2(Wb[(size_t)(2*j)*400+tid], Wb[(size_t)(2*j+1)*400+tid]);
  }
  const float fb = ((tid/100)==2) ? 1.0f : 0.0f;
  const float bc0 = bf[tid] + fb, bc1 = bb[tid] + fb;
  const float m0w0 = M0W[(size_t)seq*400 + tid];          // dir0 (first t = 0)
  const float m0w1 = M0W[(size_t)(128+seq)*400 + tid];    // dir1 (first t = TB-1)
  for (int r=0;r<50;++r){
    const int t = t0 + r;
    const float4* xr = (const float4*)(z + (size_t)seq*40000 + (size_t)t*100);
    float a0=0.f,a0b=0.f,a1=0.f,a1b=0.f;
    #pragma unroll
    for (int j=0;j<25;++j){
      float4 xv = xr[j];
      u32 pA = pkrtz(xv.x, xv.y), pB = pkrtz(xv.z, xv.w);
      a0  = dot2f(wc0[2*j],   pA, a0);
      a0b = dot2f(wc0[2*j+1], pB, a0b);
      a1  = dot2f(wc1[2*j],   pA, a1);
      a1b = dot2f(wc1[2*j+1], pB, a1b);
    }
    float g0 = a0+a0b+bc0 + ((t==0)    ? m0w0 : 0.f);
    float g1 = a1+a1b+bc1 + ((t==TB-1) ? m0w1 : 0.f);
    const size_t row = (size_t)seq*400 + t;
    Gh[row*400 + tid]                     = h16(g0);
    Gh[((size_t)51200 + row)*400 + tid]   = h16(g1);
  }
}

// ---------- k_rec2: 1 barrier/step. gates 2cols/thread + in-wave cell; proj 2cols/thread ----
__global__ __launch_bounds__(384, 1)
void k_rec2(const float* __restrict__ c0f, const float* __restrict__ c0b,
            const float* __restrict__ Pf, const float* __restrict__ Pb,
            const u32* __restrict__ Qp, const u16* __restrict__ Gh,
            float* __restrict__ out)
{
  __shared__ __align__(16) u32 h2[2][52];   // double-buffered h (f16 pairs, k pads 100..103 = 0)
  const int tid = threadIdx.x, dir = blockIdx.x>>7, seq = blockIdx.x&127;
  const float* P  = dir?Pb:Pf;
  const float* c0 = dir?c0b:c0f;

  // gates role (tid<200): cell s, half: cols cA = half*100+s (i|j), cB = cA+200 (f|o)
  const int s = tid>>1, half = tid&1;
  const int cA = half*100 + s, cB = cA + 200;
  uint4 wqA[13], wqB[13];
  float cs = 0.f;
  if (tid < 200){
    #pragma unroll
    for (int q=0;q<13;++q){
      wqA[q].x = Qp[(size_t)(dir*52+4*q+0)*400 + cA];
      wqA[q].y = Qp[(size_t)(dir*52+4*q+1)*400 + cA];
      wqA[q].z = Qp[(size_t)(dir*52+4*q+2)*400 + cA];
      wqA[q].w = Qp[(size_t)(dir*52+4*q+3)*400 + cA];
      wqB[q].x = Qp[(size_t)(dir*52+4*q+0)*400 + cB];
      wqB[q].y = Qp[(size_t)(dir*52+4*q+1)*400 + cB];
      wqB[q].z = Qp[(size_t)(dir*52+4*q+2)*400 + cB];
      wqB[q].w = Qp[(size_t)(dir*52+4*q+3)*400 + cB];
    }
    cs = c0[(size_t)seq*100 + s];           // replicated in both halves
  }
  // proj role (tid in [256,356)): cols f0=2*pl, f0+1
  const int pl = tid - 256;
  const int f0 = 2*pl;
  uint4 pw0[13], pw1[13];
  if (pl >= 0 && pl < 100){
    #pragma unroll
    for (int q=0;q<13;++q){
      u32 r0[4], r1[4];
      #pragma unroll
      for (int u=0;u<4;++u){
        int j = 4*q+u;
        r0[u] = (j<50)? pk2(P[(size_t)(2*j)*200+f0],   P[(size_t)(2*j+1)*200+f0])   : 0u;
        r1[u] = (j<50)? pk2(P[(size_t)(2*j)*200+f0+1], P[(size_t)(2*j+1)*200+f0+1]) : 0u;
      }
      pw0[q] = make_uint4(r0[0],r0[1],r0[2],r0[3]);
      pw1[q] = make_uint4(r1[0],r1[1],r1[2],r1[3]);
    }
  }
  if (tid < 104) ((u32*)h2)[tid] = 0u;      // h(-1)=0; pads of BOTH parities zeroed forever
  __syncthreads();

  const size_t gb = ((size_t)dir*51200 + (size_t)seq*400)*400;
  u16 gAn=0, gBn=0;
  if (tid<200){
    const int tf = dir ? (TB-1) : 0;
    gAn = Gh[gb + (size_t)tf*400 + cA];
    gBn = Gh[gb + (size_t)tf*400 + cB];
  }

  for (int t=0; t<=TB; ++t){
    const int p = t&1;                       // h2[p] holds h(t-1)
    if (tid<200 && t<TB){
      u16 gA = gAn, gB = gBn;
      if (t+1<TB){
        const int tn = dir ? (TB-2-t) : (t+1);
        gAn = Gh[gb + (size_t)tn*400 + cA];
        gBn = Gh[gb + (size_t)tn*400 + cB];
      }
      float aA0=0.f,aA1=0.f,aB0=0.f,aB1=0.f;
      #pragma unroll
      for (int q=0;q<13;++q){
        uint4 hv = *(const uint4*)(&h2[p][4*q]);
        aA0=dot2f(wqA[q].x,hv.x,aA0); aA1=dot2f(wqA[q].y,hv.y,aA1);
        aA0=dot2f(wqA[q].z,hv.z,aA0); aA1=dot2f(wqA[q].w,hv.w,aA1);
        aB0=dot2f(wqB[q].x,hv.x,aB0); aB1=dot2f(wqB[q].y,hv.y,aB1);
        aB0=dot2f(wqB[q].z,hv.z,aB0); aB1=dot2f(wqB[q].w,hv.w,aB1);
      }
      float aA = aA0+aA1+f16f(gA);
      float aB = aB0+aB1+f16f(gB);
      float mA = half ? tanhf_(aA) : sigf(aA);   // J : I
      float mB = sigf(aB);                       // O : F
      float oA = __shfl_xor(mA,1), oB = __shfl_xor(mB,1);
      float I = half?oA:mA, J = half?mA:oA, F = half?oB:mB, O = half?mB:oB;
      float cc = F*cs + I*J; cs = cc;
      float h = O*tanhf_(cc);
      if (!half) ((u16*)&h2[p^1][0])[s] = h16(h);
    }
    if (pl>=0 && pl<100 && t>0){               // m(t-1) = h(t-1) @ P  (pure output, off-path)
      float m00=0.f,m01=0.f,m10=0.f,m11=0.f;
      #pragma unroll
      for (int q=0;q<13;++q){
        uint4 hv = *(const uint4*)(&h2[p][4*q]);
        m00=dot2f(pw0[q].x,hv.x,m00); m01=dot2f(pw0[q].y,hv.y,m01);
        m00=dot2f(pw0[q].z,hv.z,m00); m01=dot2f(pw0[q].w,hv.w,m01);
        m10=dot2f(pw1[q].x,hv.x,m10); m11=dot2f(pw1[q].y,hv.y,m11);
        m10=dot2f(pw1[q].z,hv.z,m10); m11=dot2f(pw1[q].w,hv.w,m11);
      }
      const int tp = dir ? (TB-t) : (t-1);
      float* op = out + (size_t)seq*OUTROW + (size_t)tp*400 + dir*200 + f0;
      __builtin_nontemporal_store(m00+m01, op);
      __builtin_nontemporal_store(m10+m11, op+1);
    }
    __syncthreads();
  }
}

extern "C" void kernel_launch(void* const* d_in, const int* in_sizes, int n_in,
                              void* d_out, int out_size, void* d_ws, size_t ws_size,
                              hipStream_t stream) {
  (void)in_sizes; (void)n_in; (void)out_size; (void)ws_size;
  const float* z   = (const float*)d_in[0];
  const float* c0f = (const float*)d_in[1];
  const float* m0f = (const float*)d_in[2];
  const float* c0b = (const float*)d_in[3];
  const float* m0b = (const float*)d_in[4];
  const float* Wf  = (const float*)d_in[5];
  const float* bf  = (const float*)d_in[6];
  const float* Pf  = (const float*)d_in[7];
  const float* Wb  = (const float*)d_in[8];
  const float* bb  = (const float*)d_in[9];
  const float* Pb  = (const float*)d_in[10];

  u32*   Qp  = (u32*)d_ws;                            // 166,400 B
  float* M0W = (float*)((char*)d_ws + 196608);        // 409,600 B
  u16*   Gh  = (u16*)((char*)d_ws + 655360);          // 81,920,000 B (total ~82.6 MB)

  k_q  <<<104, 512, 0, stream>>>(Wf, Pf, Wb, Pb, Qp);
  k_m0 <<<256, 512, 0, stream>>>(m0f, m0b, Wf, Wb, M0W);
  k_g2 <<<1024,512, 0, stream>>>(z, Wf, bf, Wb, bb, M0W, Gh);
  k_rec2<<<256, 384, 0, stream>>>(c0f, c0b, Pf, Pb, Qp, Gh, (float*)d_out);
}

// Round 14
// 648.513 us; speedup vs baseline: 1.1547x; 1.1547x over previous
//
#include <hip/hip_runtime.h>
#include <stdint.h>

#define TB     400
#define OUTROW 160000   // T * 2F

typedef _Float16 half2_t __attribute__((ext_vector_type(2)));
typedef __fp16   fp16v2  __attribute__((ext_vector_type(2)));
typedef uint16_t u16;
typedef uint32_t u32;

#if defined(__has_builtin)
#  if __has_builtin(__builtin_amdgcn_fdot2)
#    define HAVE_FDOT2 1
#  endif
#endif

__device__ __forceinline__ float sigf(float x){ return 1.0f/(1.0f+__expf(-x)); }
__device__ __forceinline__ float tanhf_(float x){ float e=__expf(2.0f*x); return 1.0f-2.0f/(e+1.0f); }
__device__ __forceinline__ u16 h16(float x){ _Float16 h=(_Float16)x; return __builtin_bit_cast(u16,h); }
__device__ __forceinline__ u32 pk2(float a, float b){ return (u32)h16(a) | ((u32)h16(b)<<16); }
__device__ __forceinline__ u32 pkrtz(float a, float b){
  fp16v2 v = __builtin_amdgcn_cvt_pkrtz(a,b);
  return __builtin_bit_cast(u32, v);
}
__device__ __forceinline__ float f16f(u16 u){ return (float)__builtin_bit_cast(_Float16,u); }
__device__ __forceinline__ float dot2f(u32 w, u32 x, float acc){
#ifdef HAVE_FDOT2
  return __builtin_amdgcn_fdot2(__builtin_bit_cast(half2_t,w), __builtin_bit_cast(half2_t,x), acc, false);
#else
  half2_t a = __builtin_bit_cast(half2_t,w), b = __builtin_bit_cast(half2_t,x);
  return acc + (float)a.x*(float)b.x + (float)a.y*(float)b.y;
#endif
}

// ---------- k_q: Q = P @ W_m (100x400 per dir), f16 k-pair packed, rows 100..103 = 0 ----
__global__ __launch_bounds__(512)
void k_q(const float* __restrict__ Wf, const float* __restrict__ Pf,
         const float* __restrict__ Wb, const float* __restrict__ Pb,
         u32* __restrict__ Qp)
{
  const int b = blockIdx.x, dir = b/52, j = b%52, tid = threadIdx.x;
  const float* W = dir?Wb:Wf; const float* P = dir?Pb:Pf;
  __shared__ float pr[2][200];
  for (int i=tid;i<400;i+=512){ int u=i/200,k=i%200; int hk=2*j+u;
    pr[u][k] = (hk<100)? P[(size_t)hk*200+k] : 0.f; }
  __syncthreads();
  if (tid<400){
    float a0=0.f,a1=0.f;
    for (int k=0;k<200;++k){ float w = W[(size_t)(100+k)*400+tid]; a0 += pr[0][k]*w; a1 += pr[1][k]*w; }
    Qp[(size_t)(dir*52+j)*400+tid] = pk2(a0,a1);
  }
}

// ---------- k_m0: M0W[dir][seq][c] = m0 @ W_m (first-step recurrent term, f32) ----------
__global__ __launch_bounds__(512)
void k_m0(const float* __restrict__ m0f, const float* __restrict__ m0b,
          const float* __restrict__ Wf, const float* __restrict__ Wb,
          float* __restrict__ M0W)
{
  const int b = blockIdx.x, dir=b>>7, seq=b&127, tid=threadIdx.x;
  const float* m0 = dir?m0b:m0f; const float* W = dir?Wb:Wf;
  __shared__ float mr[200];
  if (tid<200) mr[tid] = m0[(size_t)seq*200+tid];
  __syncthreads();
  if (tid<400){
    float a=0.f;
    for (int k=0;k<200;++k) a += mr[k]*W[(size_t)(100+k)*400+tid];
    M0W[(size_t)b*400+tid] = a;
  }
}

// ---------- k_g3: G = f16(x@Wx + bias(+1 f) [+ m0@Wm @ first t]); 1 dir/thread ----------
// grid 2048: b = dir*1024 + seq*8 + chunk(50 t). Thread owns col tid (50-u32 weights).
__global__ __launch_bounds__(512)
void k_g3(const float* __restrict__ z,
          const float* __restrict__ Wf, const float* __restrict__ bf,
          const float* __restrict__ Wb, const float* __restrict__ bb,
          const float* __restrict__ M0W, u16* __restrict__ Gh)
{
  const int b = blockIdx.x, dir = b>>10, seq = (b>>3)&127, chunk = b&7;
  const int tid = threadIdx.x;
  if (tid >= 400) return;
  const float* W  = dir?Wb:Wf;
  const float* bv = dir?bb:bf;
  u32 wc[50];
  #pragma unroll
  for (int j=0;j<50;++j)
    wc[j] = pk2(W[(size_t)(2*j)*400+tid], W[(size_t)(2*j+1)*400+tid]);
  const float bc  = bv[tid] + (((tid/100)==2) ? 1.0f : 0.0f);
  const float m0w = M0W[(size_t)(dir*128+seq)*400 + tid];
  const int tfirst = dir ? (TB-1) : 0;
  for (int r=0;r<50;++r){
    const int t = chunk*50 + r;
    const float4* xr = (const float4*)(z + (size_t)seq*40000 + (size_t)t*100);
    float a0=0.f, a1=0.f;
    #pragma unroll
    for (int j=0;j<25;++j){
      float4 xv = xr[j];
      u32 pA = pkrtz(xv.x, xv.y), pB = pkrtz(xv.z, xv.w);
      a0 = dot2f(wc[2*j],   pA, a0);
      a1 = dot2f(wc[2*j+1], pB, a1);
    }
    float gg = a0 + a1 + bc + ((t==tfirst) ? m0w : 0.f);
    Gh[((size_t)dir*51200 + (size_t)seq*400 + t)*400 + tid] = h16(gg);
  }
}

// ---------- k_rec3: gates-only recurrence, 1 barrier/step, in-wave cell, h-trace out ----
__global__ __launch_bounds__(512, 1)
void k_rec3(const float* __restrict__ c0f, const float* __restrict__ c0b,
            const u32* __restrict__ Qp, const u16* __restrict__ Gh,
            u16* __restrict__ htr)
{
  __shared__ __align__(16) u32 h2[2][52];   // double-buffered h f16-pairs; slots 50,51 = pad 0
  const int tid = threadIdx.x, dir = blockIdx.x>>7, seq = blockIdx.x&127;
  const float* c0 = dir?c0b:c0f;
  const int s = tid>>2, g = tid&3;          // cell s at lanes 4s..4s+3; gate g (0:i 1:j 2:f 3:o)
  const int c = g*100 + s;
  uint4 wq[13];
  float cs = 0.f;
  if (tid < 400){
    #pragma unroll
    for (int q=0;q<13;++q){
      wq[q].x = Qp[(size_t)(dir*52+4*q+0)*400 + c];
      wq[q].y = Qp[(size_t)(dir*52+4*q+1)*400 + c];
      wq[q].z = Qp[(size_t)(dir*52+4*q+2)*400 + c];
      wq[q].w = Qp[(size_t)(dir*52+4*q+3)*400 + c];
    }
    cs = c0[(size_t)seq*100 + s];           // replicated across the 4 gate lanes
  }
  if (tid < 104) ((u32*)h2)[tid] = 0u;      // h(-1)=0; pads of both parities zero forever
  __syncthreads();

  const size_t gb = ((size_t)dir*51200 + (size_t)seq*400)*400;
  const size_t hb = (size_t)(dir*128+seq)*400;   // h-trace rows of 104 u16
  u16 gn = 0;
  if (tid<400) gn = Gh[gb + (size_t)(dir?(TB-1):0)*400 + c];

  for (int t=0; t<TB; ++t){
    const int p = t&1;
    const int tt = dir ? (TB-1-t) : t;
    if (tid < 400){
      u16 gc = gn;
      if (t+1 < TB) gn = Gh[gb + (size_t)(dir?(TB-2-t):(t+1))*400 + c];
      float a0=0.f,a1=0.f,a2=0.f,a3=0.f;
      #pragma unroll
      for (int q=0;q<13;++q){
        uint4 hv = *(const uint4*)(&h2[p][4*q]);
        a0=dot2f(wq[q].x,hv.x,a0); a1=dot2f(wq[q].y,hv.y,a1);
        a2=dot2f(wq[q].z,hv.z,a2); a3=dot2f(wq[q].w,hv.w,a3);
      }
      float a = ((a0+a1)+(a2+a3)) + f16f(gc);
      float arg = (g==1) ? a+a : a;         // tanh(x) = 2*sig(2x)-1
      float v = sigf(arg);
      float act = (g==1) ? 2.0f*v-1.0f : v;
      float bx = __shfl_xor(act,1);         // lane g^1
      float dx = __shfl_xor(act,2);         // lane g^2
      float ex = __shfl_xor(bx,2);          // lane g^3
      float I = (g==0)?act:(g==1)?bx:(g==2)?dx:ex;
      float J = (g==1)?act:(g==0)?bx:(g==3)?dx:ex;
      float F = (g==2)?act:(g==3)?bx:(g==0)?dx:ex;
      float O = (g==3)?act:(g==2)?bx:(g==1)?dx:ex;
      float cc = F*cs + I*J; cs = cc;
      float h = O*tanhf_(cc);
      if (g==0){
        u16 hx = h16(h);
        ((u16*)&h2[p^1][0])[s] = hx;        // next step's h (other buffer; 1 barrier suffices)
        htr[(hb + tt)*104 + s] = hx;        // h-trace for k_proj
      } else if (g==1 && s<4){
        htr[(hb + tt)*104 + 100 + s] = (u16)0;   // zero k-pads of the trace row
      }
    }
    __syncthreads();
  }
}

// ---------- k_proj: m(t) = h(t) @ P for all rows (off critical path) ----------
__global__ __launch_bounds__(256)
void k_proj(const float* __restrict__ Pf, const float* __restrict__ Pb,
            const u16* __restrict__ htr, float* __restrict__ out)
{
  const int b = blockIdx.x;
  const int chunk = b&7, ds = b>>3, dir = ds>>7, seq = ds&127;
  const int tid = threadIdx.x;
  if (tid >= 200) return;
  const float* P = dir?Pb:Pf;
  uint4 pw[13];
  #pragma unroll
  for (int q=0;q<13;++q){
    u32 r[4];
    #pragma unroll
    for (int u=0;u<4;++u){
      int j = 4*q+u;
      r[u] = (j<50)? pk2(P[(size_t)(2*j)*200+tid], P[(size_t)(2*j+1)*200+tid]) : 0u;
    }
    pw[q] = make_uint4(r[0],r[1],r[2],r[3]);
  }
  const size_t hb = (size_t)ds*400;
  for (int r=0;r<50;++r){
    const int t = chunk*50 + r;
    const uint4* hr = (const uint4*)(htr + (hb+t)*104);
    float m0=0.f,m1=0.f,m2=0.f,m3=0.f;
    #pragma unroll
    for (int q=0;q<13;++q){
      uint4 hv = hr[q];
      m0=dot2f(pw[q].x,hv.x,m0); m1=dot2f(pw[q].y,hv.y,m1);
      m2=dot2f(pw[q].z,hv.z,m2); m3=dot2f(pw[q].w,hv.w,m3);
    }
    __builtin_nontemporal_store((m0+m1)+(m2+m3),
        out + (size_t)seq*OUTROW + (size_t)t*400 + dir*200 + tid);
  }
}

extern "C" void kernel_launch(void* const* d_in, const int* in_sizes, int n_in,
                              void* d_out, int out_size, void* d_ws, size_t ws_size,
                              hipStream_t stream) {
  (void)in_sizes; (void)n_in; (void)out_size; (void)ws_size;
  const float* z   = (const float*)d_in[0];
  const float* c0f = (const float*)d_in[1];
  const float* m0f = (const float*)d_in[2];
  const float* c0b = (const float*)d_in[3];
  const float* m0b = (const float*)d_in[4];
  const float* Wf  = (const float*)d_in[5];
  const float* bf  = (const float*)d_in[6];
  const float* Pf  = (const float*)d_in[7];
  const float* Wb  = (const float*)d_in[8];
  const float* bb  = (const float*)d_in[9];
  const float* Pb  = (const float*)d_in[10];

  u32*   Qp  = (u32*)d_ws;                            // 166,400 B
  float* M0W = (float*)((char*)d_ws + 196608);        // 409,600 B
  u16*   Gh  = (u16*)((char*)d_ws + 655360);          // 81,920,000 B
  u16*   htr = (u16*)((char*)d_ws + 82575360);        // 21,299,200 B (total ~103.9 MB)

  k_q   <<<104, 512, 0, stream>>>(Wf, Pf, Wb, Pb, Qp);
  k_m0  <<<256, 512, 0, stream>>>(m0f, m0b, Wf, Wb, M0W);
  k_g3  <<<2048,512, 0, stream>>>(z, Wf, bf, Wb, bb, M0W, Gh);
  k_rec3<<<256, 512, 0, stream>>>(c0f, c0b, Qp, Gh, htr);
  k_proj<<<2048,256, 0, stream>>>(Pf, Pb, htr, (float*)d_out);
}

// Round 15
// 621.853 us; speedup vs baseline: 1.2042x; 1.0429x over previous
//
#include <hip/hip_runtime.h>
#include <stdint.h>

#define TB     400
#define OUTROW 160000   // T * 2F

typedef _Float16 half2_t __attribute__((ext_vector_type(2)));
typedef __fp16   fp16v2  __attribute__((ext_vector_type(2)));
typedef _Float16 f16x8 __attribute__((ext_vector_type(8)));
typedef float    f32x4 __attribute__((ext_vector_type(4)));
typedef uint16_t u16;
typedef uint32_t u32;

__device__ __forceinline__ float sigf(float x){ return 1.0f/(1.0f+__expf(-x)); }
__device__ __forceinline__ float tanhf_(float x){ float e=__expf(2.0f*x); return 1.0f-2.0f/(e+1.0f); }
__device__ __forceinline__ u16 h16(float x){ _Float16 h=(_Float16)x; return __builtin_bit_cast(u16,h); }
__device__ __forceinline__ u32 pk2(float a, float b){ return (u32)h16(a) | ((u32)h16(b)<<16); }
__device__ __forceinline__ float f16f(u16 u){ return (float)__builtin_bit_cast(_Float16,u); }

// f16-pair MAC via explicit v_fma_mix_f32 (2 VALU ops per pair, f32 accumulate)
__device__ __forceinline__ float fmal(u32 a, u32 b, float c){
  float d;
  asm("v_fma_mix_f32 %0, %1, %2, %3 op_sel_hi:[1,1,0]" : "=v"(d) : "v"(a), "v"(b), "v"(c));
  return d;
}
__device__ __forceinline__ float fmah(u32 a, u32 b, float c){
  float d;
  asm("v_fma_mix_f32 %0, %1, %2, %3 op_sel:[1,1,0] op_sel_hi:[1,1,0]" : "=v"(d) : "v"(a), "v"(b), "v"(c));
  return d;
}
__device__ __forceinline__ float dmix(u32 w, u32 x, float acc){ return fmah(w,x, fmal(w,x,acc)); }

// ---------- k_q: Q = P @ W_m (100x400 per dir), f16 k-pair packed, rows 100..103 = 0 ----
__global__ __launch_bounds__(512)
void k_q(const float* __restrict__ Wf, const float* __restrict__ Pf,
         const float* __restrict__ Wb, const float* __restrict__ Pb,
         u32* __restrict__ Qp)
{
  const int b = blockIdx.x, dir = b/52, j = b%52, tid = threadIdx.x;
  const float* W = dir?Wb:Wf; const float* P = dir?Pb:Pf;
  __shared__ float pr[2][200];
  for (int i=tid;i<400;i+=512){ int u=i/200,k=i%200; int hk=2*j+u;
    pr[u][k] = (hk<100)? P[(size_t)hk*200+k] : 0.f; }
  __syncthreads();
  if (tid<400){
    float a0=0.f,a1=0.f;
    for (int k=0;k<200;++k){ float w = W[(size_t)(100+k)*400+tid]; a0 += pr[0][k]*w; a1 += pr[1][k]*w; }
    Qp[(size_t)(dir*52+j)*400+tid] = pk2(a0,a1);
  }
}

// ---------- k_m0: M0W[dir][seq][c] = m0 @ W_m (first-step recurrent term, f32) ----------
__global__ __launch_bounds__(512)
void k_m0(const float* __restrict__ m0f, const float* __restrict__ m0b,
          const float* __restrict__ Wf, const float* __restrict__ Wb,
          float* __restrict__ M0W)
{
  const int b = blockIdx.x, dir=b>>7, seq=b&127, tid=threadIdx.x;
  const float* m0 = dir?m0b:m0f; const float* W = dir?Wb:Wf;
  __shared__ float mr[200];
  if (tid<200) mr[tid] = m0[(size_t)seq*200+tid];
  __syncthreads();
  if (tid<400){
    float a=0.f;
    for (int k=0;k<200;++k) a += mr[k]*W[(size_t)(100+k)*400+tid];
    M0W[(size_t)b*400+tid] = a;
  }
}

// ---------- k_g4: G = f16(x@Wx + bias(+1 f) [+ m0@Wm @ first t]) via MFMA ----------
// block = (dir,seq); 5 chunks x 80 rows; A-frags staged in LDS; B (W) frags in regs/AGPR.
// Fragment layouts (verified by R8 pass): A elem (m,k): lane = m|((k>>3 &3)<<4), half k&7.
// D: col = lane&15 (N), row = (lane>>4)*4 + r (M).
__global__ __launch_bounds__(512, 1)
void k_g4(const float* __restrict__ z,
          const float* __restrict__ Wf, const float* __restrict__ bf,
          const float* __restrict__ Wb, const float* __restrict__ bb,
          const float* __restrict__ M0W, u16* __restrict__ Gh)
{
  __shared__ __align__(16) u16 xa[5][4][512];   // 5 M-tiles x 4 K-tiles, 20 KB
  const int tid = threadIdx.x, wv = tid>>6, lane = tid&63;
  const int l15 = lane&15, lg = lane>>4;
  const int dir = blockIdx.x>>7, seq = blockIdx.x&127;
  const float* W  = dir?Wb:Wf;
  const float* bv = dir?bb:bf;

  const int nnt = (wv==0)?4:3;
  const int ntl[4] = {wv, wv+8, wv+16, 24};

  f16x8 wb_[4][4];                               // B-frags [ntile][ktile]
  float bias[4], m0w[4];
  #pragma unroll
  for (int i=0;i<4;++i) if (i<nnt){
    const int col = ntl[i]*16 + l15;
    #pragma unroll
    for (int kt=0;kt<4;++kt){
      f16x8 v;
      #pragma unroll
      for (int e=0;e<8;++e){
        int k = kt*32 + lg*8 + e;
        v[e] = (_Float16)((k<100)? W[(size_t)k*400+col] : 0.f);
      }
      wb_[i][kt]=v;
    }
    bias[i] = bv[col] + (((col/100)==2)?1.0f:0.0f);
    m0w[i]  = M0W[(size_t)(dir*128+seq)*400 + col];
  }
  const int tfirst = dir?(TB-1):0;

  for (int i=tid;i<10240;i+=512) ((u16*)xa)[i] = (u16)0;   // zero pads once (k>=100 never rewritten)
  __syncthreads();

  for (int chunk=0; chunk<5; ++chunk){
    for (int i=tid;i<8000;i+=512){
      int r = i/100, k = i%100;
      int t = chunk*80 + r;
      float v = z[(size_t)seq*40000 + (size_t)t*100 + k];
      int mt = r>>4, m = r&15, kt = k>>5, kk = k&31;
      xa[mt][kt][(m|((kk>>3)<<4))*8 + (kk&7)] = h16(v);
    }
    __syncthreads();
    #pragma unroll
    for (int mt=0; mt<5; ++mt){
      f16x8 af[4];
      #pragma unroll
      for (int kt=0;kt<4;++kt)
        af[kt] = *reinterpret_cast<const f16x8*>(&xa[mt][kt][lane*8]);
      #pragma unroll
      for (int i=0;i<4;++i) if (i<nnt){
        f32x4 acc = {0.f,0.f,0.f,0.f};
        #pragma unroll
        for (int kt=0;kt<4;++kt)
          acc = __builtin_amdgcn_mfma_f32_16x16x32_f16(af[kt], wb_[i][kt], acc, 0,0,0);
        const int col = ntl[i]*16 + l15;
        #pragma unroll
        for (int r=0;r<4;++r){
          int t = chunk*80 + mt*16 + lg*4 + r;
          float gv = acc[r] + bias[i] + ((t==tfirst)? m0w[i] : 0.f);
          Gh[((size_t)dir*51200 + (size_t)seq*400 + t)*400 + col] = h16(gv);
        }
      }
    }
    __syncthreads();
  }
}

// ---------- k_rec4: gates-only recurrence, fma_mix MACs, 1 barrier/step, h-trace out ----
__global__ __launch_bounds__(448, 1)
void k_rec4(const float* __restrict__ c0f, const float* __restrict__ c0b,
            const u32* __restrict__ Qp, const u16* __restrict__ Gh,
            u16* __restrict__ htr)
{
  __shared__ __align__(16) u32 h2[2][52];   // double-buffered h f16-pairs; slots 50,51 pad 0
  const int tid = threadIdx.x, dir = blockIdx.x>>7, seq = blockIdx.x&127;
  const float* c0 = dir?c0b:c0f;
  const int s = tid>>2, g = tid&3;          // cell s at lanes 4s..4s+3; gate g (0:i 1:j 2:f 3:o)
  const int c = g*100 + s;
  uint4 wq[13];
  float cs = 0.f;
  if (tid < 400){
    #pragma unroll
    for (int q=0;q<13;++q){
      wq[q].x = Qp[(size_t)(dir*52+4*q+0)*400 + c];
      wq[q].y = Qp[(size_t)(dir*52+4*q+1)*400 + c];
      wq[q].z = Qp[(size_t)(dir*52+4*q+2)*400 + c];
      wq[q].w = Qp[(size_t)(dir*52+4*q+3)*400 + c];
    }
    cs = c0[(size_t)seq*100 + s];
  }
  if (tid < 104) ((u32*)h2)[tid] = 0u;
  __syncthreads();

  const size_t hb = (size_t)(dir*128+seq)*400;
  const u16* gptr = Gh + ((size_t)dir*51200 + (size_t)seq*400 + (dir?(TB-1):0))*400 + c;
  const intptr_t gstep = dir ? -400 : 400;
  u16 gn = 0;
  if (tid<400) gn = *gptr;

  for (int t=0; t<TB; ++t){
    const int p = t&1;
    const int tt = dir ? (TB-1-t) : t;
    if (tid < 400){
      u16 gc = gn;
      gptr += gstep;
      if (t+1 < TB) gn = *gptr;
      float a0=0.f,a1=0.f,a2=0.f,a3=0.f;
      #pragma unroll
      for (int q=0;q<13;++q){
        uint4 hv = *(const uint4*)(&h2[p][4*q]);
        a0=dmix(wq[q].x,hv.x,a0); a1=dmix(wq[q].y,hv.y,a1);
        a2=dmix(wq[q].z,hv.z,a2); a3=dmix(wq[q].w,hv.w,a3);
      }
      float a = ((a0+a1)+(a2+a3)) + f16f(gc);
      float arg = (g==1) ? a+a : a;         // tanh(x) = 2*sig(2x)-1
      float v = sigf(arg);
      float act = (g==1) ? 2.0f*v-1.0f : v;
      float bx = __shfl_xor(act,1);
      float dx = __shfl_xor(act,2);
      float ex = __shfl_xor(bx,2);
      float I = (g==0)?act:(g==1)?bx:(g==2)?dx:ex;
      float J = (g==1)?act:(g==0)?bx:(g==3)?dx:ex;
      float F = (g==2)?act:(g==3)?bx:(g==0)?dx:ex;
      float O = (g==3)?act:(g==2)?bx:(g==1)?dx:ex;
      float cc = F*cs + I*J; cs = cc;
      float h = O*tanhf_(cc);
      if (g==0){
        u16 hx = h16(h);
        ((u16*)&h2[p^1][0])[s] = hx;
        htr[(hb + tt)*104 + s] = hx;
      } else if (g==1 && s<4){
        htr[(hb + tt)*104 + 100 + s] = (u16)0;
      }
    }
    __syncthreads();
  }
}

// ---------- k_proj: m(t) = h(t) @ P for all rows (off critical path), fma_mix ----------
__global__ __launch_bounds__(256)
void k_proj(const float* __restrict__ Pf, const float* __restrict__ Pb,
            const u16* __restrict__ htr, float* __restrict__ out)
{
  const int b = blockIdx.x;
  const int chunk = b&7, ds = b>>3, dir = ds>>7, seq = ds&127;
  const int tid = threadIdx.x;
  if (tid >= 200) return;
  const float* P = dir?Pb:Pf;
  uint4 pw[13];
  #pragma unroll
  for (int q=0;q<13;++q){
    u32 r[4];
    #pragma unroll
    for (int u=0;u<4;++u){
      int j = 4*q+u;
      r[u] = (j<50)? pk2(P[(size_t)(2*j)*200+tid], P[(size_t)(2*j+1)*200+tid]) : 0u;
    }
    pw[q] = make_uint4(r[0],r[1],r[2],r[3]);
  }
  const size_t hb = (size_t)ds*400;
  for (int r=0;r<50;++r){
    const int t = chunk*50 + r;
    const uint4* hr = (const uint4*)(htr + (hb+t)*104);
    float m0=0.f,m1=0.f,m2=0.f,m3=0.f;
    #pragma unroll
    for (int q=0;q<13;++q){
      uint4 hv = hr[q];
      m0=dmix(pw[q].x,hv.x,m0); m1=dmix(pw[q].y,hv.y,m1);
      m2=dmix(pw[q].z,hv.z,m2); m3=dmix(pw[q].w,hv.w,m3);
    }
    __builtin_nontemporal_store((m0+m1)+(m2+m3),
        out + (size_t)seq*OUTROW + (size_t)t*400 + dir*200 + tid);
  }
}

extern "C" void kernel_launch(void* const* d_in, const int* in_sizes, int n_in,
                              void* d_out, int out_size, void* d_ws, size_t ws_size,
                              hipStream_t stream) {
  (void)in_sizes; (void)n_in; (void)out_size; (void)ws_size;
  const float* z   = (const float*)d_in[0];
  const float* c0f = (const float*)d_in[1];
  const float* m0f = (const float*)d_in[2];
  const float* c0b = (const float*)d_in[3];
  const float* m0b = (const float*)d_in[4];
  const float* Wf  = (const float*)d_in[5];
  const float* bf  = (const float*)d_in[6];
  const float* Pf  = (const float*)d_in[7];
  const float* Wb  = (const float*)d_in[8];
  const float* bb  = (const float*)d_in[9];
  const float* Pb  = (const float*)d_in[10];

  u32*   Qp  = (u32*)d_ws;                            // 166,400 B
  float* M0W = (float*)((char*)d_ws + 196608);        // 409,600 B
  u16*   Gh  = (u16*)((char*)d_ws + 655360);          // 81,920,000 B
  u16*   htr = (u16*)((char*)d_ws + 82575360);        // 21,299,200 B (total ~103.9 MB)

  k_q   <<<104, 512, 0, stream>>>(Wf, Pf, Wb, Pb, Qp);
  k_m0  <<<256, 512, 0, stream>>>(m0f, m0b, Wf, Wb, M0W);
  k_g4  <<<256, 512, 0, stream>>>(z, Wf, bf, Wb, bb, M0W, Gh);
  k_rec4<<<256, 448, 0, stream>>>(c0f, c0b, Qp, Gh, htr);
  k_proj<<<2048,256, 0, stream>>>(Pf, Pb, htr, (float*)d_out);
}

// Round 16
// 478.737 us; speedup vs baseline: 1.5642x; 1.2989x over previous
//
#include <hip/hip_runtime.h>
#include <stdint.h>

#define TB     400
#define OUTROW 160000   // T * 2F

typedef _Float16 half2_t __attribute__((ext_vector_type(2)));
typedef _Float16 f16x8 __attribute__((ext_vector_type(8)));
typedef float    f32x4 __attribute__((ext_vector_type(4)));
typedef uint16_t u16;
typedef uint32_t u32;

__device__ __forceinline__ float sigf(float x){ return 1.0f/(1.0f+__expf(-x)); }
__device__ __forceinline__ float tanhf_(float x){ float e=__expf(2.0f*x); return 1.0f-2.0f/(e+1.0f); }
__device__ __forceinline__ u16 h16(float x){ _Float16 h=(_Float16)x; return __builtin_bit_cast(u16,h); }
__device__ __forceinline__ u32 pk2(float a, float b){ return (u32)h16(a) | ((u32)h16(b)<<16); }
__device__ __forceinline__ float f16f(u16 u){ return (float)__builtin_bit_cast(_Float16,u); }
__device__ __forceinline__ float dot2f(u32 w, u32 x, float acc){
  return __builtin_amdgcn_fdot2(__builtin_bit_cast(half2_t,w), __builtin_bit_cast(half2_t,x), acc, false);
}
// DPP quad-permute adds (in-quad butterfly, VALU-only — no DS pipe)
__device__ __forceinline__ float qxor1(float x){
  return __builtin_bit_cast(float, __builtin_amdgcn_mov_dpp(__builtin_bit_cast(int,x), 0xB1, 0xf, 0xf, true)); // quad_perm(1,0,3,2)
}
__device__ __forceinline__ float qxor2(float x){
  return __builtin_bit_cast(float, __builtin_amdgcn_mov_dpp(__builtin_bit_cast(int,x), 0x4E, 0xf, 0xf, true)); // quad_perm(2,3,0,1)
}

// ---------- k_q: Q = P @ W_m (100x400 per dir), f16 k-pair packed, 52 pair-rows ----------
__global__ __launch_bounds__(512)
void k_q(const float* __restrict__ Wf, const float* __restrict__ Pf,
         const float* __restrict__ Wb, const float* __restrict__ Pb,
         u32* __restrict__ Qp)
{
  const int b = blockIdx.x, dir = b/52, j = b%52, tid = threadIdx.x;
  const float* W = dir?Wb:Wf; const float* P = dir?Pb:Pf;
  __shared__ float pr[2][200];
  for (int i=tid;i<400;i+=512){ int u=i/200,k=i%200; int hk=2*j+u;
    pr[u][k] = (hk<100)? P[(size_t)hk*200+k] : 0.f; }
  __syncthreads();
  if (tid<400){
    float a0=0.f,a1=0.f;
    for (int k=0;k<200;++k){ float w = W[(size_t)(100+k)*400+tid]; a0 += pr[0][k]*w; a1 += pr[1][k]*w; }
    Qp[(size_t)(dir*52+j)*400+tid] = pk2(a0,a1);
  }
}

// ---------- k_m0: M0W[dir][seq][c] = m0 @ W_m (first-step recurrent term, f32) ----------
__global__ __launch_bounds__(512)
void k_m0(const float* __restrict__ m0f, const float* __restrict__ m0b,
          const float* __restrict__ Wf, const float* __restrict__ Wb,
          float* __restrict__ M0W)
{
  const int b = blockIdx.x, dir=b>>7, seq=b&127, tid=threadIdx.x;
  const float* m0 = dir?m0b:m0f; const float* W = dir?Wb:Wf;
  __shared__ float mr[200];
  if (tid<200) mr[tid] = m0[(size_t)seq*200+tid];
  __syncthreads();
  if (tid<400){
    float a=0.f;
    for (int k=0;k<200;++k) a += mr[k]*W[(size_t)(100+k)*400+tid];
    M0W[(size_t)b*400+tid] = a;
  }
}

// ---------- k_g4: G = f16(x@Wx + bias(+1 f) [+ m0@Wm @ first t]) via MFMA (R15-proven) ----
__global__ __launch_bounds__(512, 1)
void k_g4(const float* __restrict__ z,
          const float* __restrict__ Wf, const float* __restrict__ bf,
          const float* __restrict__ Wb, const float* __restrict__ bb,
          const float* __restrict__ M0W, u16* __restrict__ Gh)
{
  __shared__ __align__(16) u16 xa[5][4][512];   // 5 M-tiles x 4 K-tiles, 20 KB
  const int tid = threadIdx.x, wv = tid>>6, lane = tid&63;
  const int l15 = lane&15, lg = lane>>4;
  const int dir = blockIdx.x>>7, seq = blockIdx.x&127;
  const float* W  = dir?Wb:Wf;
  const float* bv = dir?bb:bf;

  const int nnt = (wv==0)?4:3;
  const int ntl[4] = {wv, wv+8, wv+16, 24};

  f16x8 wb_[4][4];
  float bias[4], m0w[4];
  #pragma unroll
  for (int i=0;i<4;++i) if (i<nnt){
    const int col = ntl[i]*16 + l15;
    #pragma unroll
    for (int kt=0;kt<4;++kt){
      f16x8 v;
      #pragma unroll
      for (int e=0;e<8;++e){
        int k = kt*32 + lg*8 + e;
        v[e] = (_Float16)((k<100)? W[(size_t)k*400+col] : 0.f);
      }
      wb_[i][kt]=v;
    }
    bias[i] = bv[col] + (((col/100)==2)?1.0f:0.0f);
    m0w[i]  = M0W[(size_t)(dir*128+seq)*400 + col];
  }
  const int tfirst = dir?(TB-1):0;

  for (int i=tid;i<10240;i+=512) ((u16*)xa)[i] = (u16)0;
  __syncthreads();

  for (int chunk=0; chunk<5; ++chunk){
    for (int i=tid;i<8000;i+=512){
      int r = i/100, k = i%100;
      int t = chunk*80 + r;
      float v = z[(size_t)seq*40000 + (size_t)t*100 + k];
      int mt = r>>4, m = r&15, kt = k>>5, kk = k&31;
      xa[mt][kt][(m|((kk>>3)<<4))*8 + (kk&7)] = h16(v);
    }
    __syncthreads();
    #pragma unroll
    for (int mt=0; mt<5; ++mt){
      f16x8 af[4];
      #pragma unroll
      for (int kt=0;kt<4;++kt)
        af[kt] = *reinterpret_cast<const f16x8*>(&xa[mt][kt][lane*8]);
      #pragma unroll
      for (int i=0;i<4;++i) if (i<nnt){
        f32x4 acc = {0.f,0.f,0.f,0.f};
        #pragma unroll
        for (int kt=0;kt<4;++kt)
          acc = __builtin_amdgcn_mfma_f32_16x16x32_f16(af[kt], wb_[i][kt], acc, 0,0,0);
        const int col = ntl[i]*16 + l15;
        #pragma unroll
        for (int r=0;r<4;++r){
          int t = chunk*80 + mt*16 + lg*4 + r;
          float gv = acc[r] + bias[i] + ((t==tfirst)? m0w[i] : 0.f);
          Gh[((size_t)dir*51200 + (size_t)seq*400 + t)*400 + col] = h16(gv);
        }
      }
    }
    __syncthreads();
  }
}

// ---------- k_rec5: (s, kq) mapping — all 4 gates/lane over K/4, DPP quad-reduce ----------
// K padded to 128 elements (64 u32); quarter kq = u32 [16kq,16kq+16) = 4 b128 reads.
// Lane adds its own gate-kq G before the reduce; butterfly distributes it. 1 barrier/step.
__global__ __launch_bounds__(448, 1)
void k_rec5(const float* __restrict__ c0f, const float* __restrict__ c0b,
            const u32* __restrict__ Qp, const u16* __restrict__ Gh,
            u16* __restrict__ htr)
{
  __shared__ __align__(16) u32 h2q[2][64];  // double-buffered h f16-pairs, elements 100..127 = 0
  const int tid = threadIdx.x, dir = blockIdx.x>>7, seq = blockIdx.x&127;
  const float* c0 = dir?c0b:c0f;
  const int s = tid>>2, kq = tid&3;         // cell s on quad 4s..4s+3; lane owns K-quarter kq

  uint4 wq[4][4];                           // [gate][quad within quarter] = 64 u32
  float cs = 0.f;
  if (tid < 400){
    #pragma unroll
    for (int g=0;g<4;++g){
      const int col = g*100 + s;
      #pragma unroll
      for (int q=0;q<4;++q){
        u32 r[4];
        #pragma unroll
        for (int u=0;u<4;++u){
          int p = 16*kq + 4*q + u;          // pair index (elements 2p,2p+1)
          r[u] = (p<52)? Qp[(size_t)(dir*52+p)*400 + col] : 0u;
        }
        wq[g][q] = make_uint4(r[0],r[1],r[2],r[3]);
      }
    }
    cs = c0[(size_t)seq*100 + s];           // replicated across the quad
  }
  if (tid < 128) ((u32*)h2q)[tid] = 0u;     // h(-1)=0 + permanent pads (both parities)
  __syncthreads();

  const size_t hb = (size_t)(dir*128+seq)*400;
  const u16* gptr = Gh + ((size_t)dir*51200 + (size_t)seq*400 + (dir?(TB-1):0))*400 + kq*100 + s;
  const intptr_t gstep = dir ? -400 : 400;
  u16 gn = 0;
  if (tid<400) gn = *gptr;

  for (int t=0; t<TB; ++t){
    const int p = t&1;
    const int tt = dir ? (TB-1-t) : t;
    if (tid < 400){
      u16 gc = gn;
      gptr += gstep;
      if (t+1 < TB) gn = *gptr;
      float acc[4];
      acc[0]=0.f; acc[1]=0.f; acc[2]=0.f; acc[3]=0.f;
      #pragma unroll
      for (int q=0;q<4;++q){
        uint4 hv = *(const uint4*)(&h2q[p][16*kq + 4*q]);
        acc[0]=dot2f(wq[0][q].x,hv.x,acc[0]); acc[0]=dot2f(wq[0][q].y,hv.y,acc[0]);
        acc[0]=dot2f(wq[0][q].z,hv.z,acc[0]); acc[0]=dot2f(wq[0][q].w,hv.w,acc[0]);
        acc[1]=dot2f(wq[1][q].x,hv.x,acc[1]); acc[1]=dot2f(wq[1][q].y,hv.y,acc[1]);
        acc[1]=dot2f(wq[1][q].z,hv.z,acc[1]); acc[1]=dot2f(wq[1][q].w,hv.w,acc[1]);
        acc[2]=dot2f(wq[2][q].x,hv.x,acc[2]); acc[2]=dot2f(wq[2][q].y,hv.y,acc[2]);
        acc[2]=dot2f(wq[2][q].z,hv.z,acc[2]); acc[2]=dot2f(wq[2][q].w,hv.w,acc[2]);
        acc[3]=dot2f(wq[3][q].x,hv.x,acc[3]); acc[3]=dot2f(wq[3][q].y,hv.y,acc[3]);
        acc[3]=dot2f(wq[3][q].z,hv.z,acc[3]); acc[3]=dot2f(wq[3][q].w,hv.w,acc[3]);
      }
      acc[kq] += f16f(gc);                  // own gate's G (bias etc. baked in) pre-reduce
      float full[4];
      #pragma unroll
      for (int g=0;g<4;++g){
        float a1 = acc[g] + qxor1(acc[g]);
        full[g]  = a1 + qxor2(a1);          // whole quad now has the complete pre-activation
      }
      float I = sigf(full[0]);
      float J = tanhf_(full[1]);
      float F = sigf(full[2] );             // forget bias already in G
      float O = sigf(full[3]);
      float cc = F*cs + I*J; cs = cc;       // redundant x4, deterministic
      float h = O*tanhf_(cc);
      if (kq==0){
        u16 hx = h16(h);
        ((u16*)&h2q[p^1][0])[s] = hx;       // padded layout: u16 index == s
        htr[(hb + tt)*104 + s] = hx;
      } else if (kq==1 && s<4){
        htr[(hb + tt)*104 + 100 + s] = (u16)0;
      }
    }
    __syncthreads();
  }
}

// ---------- k_proj: m(t) = h(t) @ P for all rows (off critical path), fdot2 ----------
__global__ __launch_bounds__(256)
void k_proj(const float* __restrict__ Pf, const float* __restrict__ Pb,
            const u16* __restrict__ htr, float* __restrict__ out)
{
  const int b = blockIdx.x;
  const int chunk = b&7, ds = b>>3, dir = ds>>7, seq = ds&127;
  const int tid = threadIdx.x;
  if (tid >= 200) return;
  const float* P = dir?Pb:Pf;
  uint4 pw[13];
  #pragma unroll
  for (int q=0;q<13;++q){
    u32 r[4];
    #pragma unroll
    for (int u=0;u<4;++u){
      int j = 4*q+u;
      r[u] = (j<50)? pk2(P[(size_t)(2*j)*200+tid], P[(size_t)(2*j+1)*200+tid]) : 0u;
    }
    pw[q] = make_uint4(r[0],r[1],r[2],r[3]);
  }
  const size_t hb = (size_t)ds*400;
  for (int r=0;r<50;++r){
    const int t = chunk*50 + r;
    const uint4* hr = (const uint4*)(htr + (hb+t)*104);
    float m0=0.f,m1=0.f,m2=0.f,m3=0.f;
    #pragma unroll
    for (int q=0;q<13;++q){
      uint4 hv = hr[q];
      m0=dot2f(pw[q].x,hv.x,m0); m1=dot2f(pw[q].y,hv.y,m1);
      m2=dot2f(pw[q].z,hv.z,m2); m3=dot2f(pw[q].w,hv.w,m3);
    }
    __builtin_nontemporal_store((m0+m1)+(m2+m3),
        out + (size_t)seq*OUTROW + (size_t)t*400 + dir*200 + tid);
  }
}

extern "C" void kernel_launch(void* const* d_in, const int* in_sizes, int n_in,
                              void* d_out, int out_size, void* d_ws, size_t ws_size,
                              hipStream_t stream) {
  (void)in_sizes; (void)n_in; (void)out_size; (void)ws_size;
  const float* z   = (const float*)d_in[0];
  const float* c0f = (const float*)d_in[1];
  const float* m0f = (const float*)d_in[2];
  const float* c0b = (const float*)d_in[3];
  const float* m0b = (const float*)d_in[4];
  const float* Wf  = (const float*)d_in[5];
  const float* bf  = (const float*)d_in[6];
  const float* Pf  = (const float*)d_in[7];
  const float* Wb  = (const float*)d_in[8];
  const float* bb  = (const float*)d_in[9];
  const float* Pb  = (const float*)d_in[10];

  u32*   Qp  = (u32*)d_ws;                            // 166,400 B
  float* M0W = (float*)((char*)d_ws + 196608);        // 409,600 B
  u16*   Gh  = (u16*)((char*)d_ws + 655360);          // 81,920,000 B
  u16*   htr = (u16*)((char*)d_ws + 82575360);        // 21,299,200 B (total ~103.9 MB)

  k_q   <<<104, 512, 0, stream>>>(Wf, Pf, Wb, Pb, Qp);
  k_m0  <<<256, 512, 0, stream>>>(m0f, m0b, Wf, Wb, M0W);
  k_g4  <<<256, 512, 0, stream>>>(z, Wf, bf, Wb, bb, M0W, Gh);
  k_rec5<<<256, 448, 0, stream>>>(c0f, c0b, Qp, Gh, htr);
  k_proj<<<2048,256, 0, stream>>>(Pf, Pb, htr, (float*)d_out);
}

// Round 17
// 323.837 us; speedup vs baseline: 2.3124x; 1.4783x over previous
//
#include <hip/hip_runtime.h>
#include <stdint.h>

#define TB     400
#define OUTROW 160000   // T * 2F

typedef _Float16 half2_t __attribute__((ext_vector_type(2)));
typedef _Float16 f16x8 __attribute__((ext_vector_type(8)));
typedef float    f32x4 __attribute__((ext_vector_type(4)));
typedef uint16_t u16;
typedef uint32_t u32;

__device__ __forceinline__ float sigf(float x){ return 1.0f/(1.0f+__expf(-x)); }
__device__ __forceinline__ float tanhf_(float x){ float e=__expf(2.0f*x); return 1.0f-2.0f/(e+1.0f); }
__device__ __forceinline__ u16 h16(float x){ _Float16 h=(_Float16)x; return __builtin_bit_cast(u16,h); }
__device__ __forceinline__ u32 pk2(float a, float b){ return (u32)h16(a) | ((u32)h16(b)<<16); }
__device__ __forceinline__ float f16f(u16 u){ return (float)__builtin_bit_cast(_Float16,u); }
__device__ __forceinline__ float dot2f(u32 w, u32 x, float acc){
  return __builtin_amdgcn_fdot2(__builtin_bit_cast(half2_t,w), __builtin_bit_cast(half2_t,x), acc, false);
}
// DPP quad-permute moves (VALU-only cross-lane within quad)
__device__ __forceinline__ float qxor1(float x){
  return __builtin_bit_cast(float, __builtin_amdgcn_mov_dpp(__builtin_bit_cast(int,x), 0xB1, 0xf, 0xf, true)); // quad_perm(1,0,3,2)
}
__device__ __forceinline__ float qxor2(float x){
  return __builtin_bit_cast(float, __builtin_amdgcn_mov_dpp(__builtin_bit_cast(int,x), 0x4E, 0xf, 0xf, true)); // quad_perm(2,3,0,1)
}

// ---------- k_prep: blocks 0..103 compute Qp (= P @ W_m, f16 pairs); 104..359 compute M0W ----
__global__ __launch_bounds__(512)
void k_prep(const float* __restrict__ Wf, const float* __restrict__ Pf,
            const float* __restrict__ Wb, const float* __restrict__ Pb,
            const float* __restrict__ m0f, const float* __restrict__ m0b,
            u32* __restrict__ Qp, float* __restrict__ M0W)
{
  const int b = blockIdx.x, tid = threadIdx.x;
  if (b < 104){
    const int dir = b/52, j = b%52;
    const float* W = dir?Wb:Wf; const float* P = dir?Pb:Pf;
    __shared__ float pr[2][200];
    for (int i=tid;i<400;i+=512){ int u=i/200,k=i%200; int hk=2*j+u;
      pr[u][k] = (hk<100)? P[(size_t)hk*200+k] : 0.f; }
    __syncthreads();
    if (tid<400){
      float a0=0.f,a1=0.f;
      for (int k=0;k<200;++k){ float w = W[(size_t)(100+k)*400+tid]; a0 += pr[0][k]*w; a1 += pr[1][k]*w; }
      Qp[(size_t)(dir*52+j)*400+tid] = pk2(a0,a1);
    }
  } else {
    const int bb2 = b-104, dir = bb2>>7, seq = bb2&127;
    const float* m0 = dir?m0b:m0f; const float* W = dir?Wb:Wf;
    __shared__ float mr[200];
    if (tid<200) mr[tid] = m0[(size_t)seq*200+tid];
    __syncthreads();
    if (tid<400){
      float a=0.f;
      for (int k=0;k<200;++k) a += mr[k]*W[(size_t)(100+k)*400+tid];
      M0W[(size_t)bb2*400+tid] = a;
    }
  }
}

// ---------- k_g4: G = f16(x@Wx + bias(+1 f) [+ m0@Wm @ first t]) via MFMA (proven) ----------
__global__ __launch_bounds__(512, 1)
void k_g4(const float* __restrict__ z,
          const float* __restrict__ Wf, const float* __restrict__ bf,
          const float* __restrict__ Wb, const float* __restrict__ bb,
          const float* __restrict__ M0W, u16* __restrict__ Gh)
{
  __shared__ __align__(16) u16 xa[5][4][512];   // 5 M-tiles x 4 K-tiles, 20 KB
  const int tid = threadIdx.x, wv = tid>>6, lane = tid&63;
  const int l15 = lane&15, lg = lane>>4;
  const int dir = blockIdx.x>>7, seq = blockIdx.x&127;
  const float* W  = dir?Wb:Wf;
  const float* bv = dir?bb:bf;

  const int nnt = (wv==0)?4:3;
  const int ntl[4] = {wv, wv+8, wv+16, 24};

  f16x8 wb_[4][4];
  float bias[4], m0w[4];
  #pragma unroll
  for (int i=0;i<4;++i) if (i<nnt){
    const int col = ntl[i]*16 + l15;
    #pragma unroll
    for (int kt=0;kt<4;++kt){
      f16x8 v;
      #pragma unroll
      for (int e=0;e<8;++e){
        int k = kt*32 + lg*8 + e;
        v[e] = (_Float16)((k<100)? W[(size_t)k*400+col] : 0.f);
      }
      wb_[i][kt]=v;
    }
    bias[i] = bv[col] + (((col/100)==2)?1.0f:0.0f);
    m0w[i]  = M0W[(size_t)(dir*128+seq)*400 + col];
  }
  const int tfirst = dir?(TB-1):0;

  for (int i=tid;i<10240;i+=512) ((u16*)xa)[i] = (u16)0;
  __syncthreads();

  for (int chunk=0; chunk<5; ++chunk){
    for (int i=tid;i<8000;i+=512){
      int r = i/100, k = i%100;
      int t = chunk*80 + r;
      float v = z[(size_t)seq*40000 + (size_t)t*100 + k];
      int mt = r>>4, m = r&15, kt = k>>5, kk = k&31;
      xa[mt][kt][(m|((kk>>3)<<4))*8 + (kk&7)] = h16(v);
    }
    __syncthreads();
    #pragma unroll
    for (int mt=0; mt<5; ++mt){
      f16x8 af[4];
      #pragma unroll
      for (int kt=0;kt<4;++kt)
        af[kt] = *reinterpret_cast<const f16x8*>(&xa[mt][kt][lane*8]);
      #pragma unroll
      for (int i=0;i<4;++i) if (i<nnt){
        f32x4 acc = {0.f,0.f,0.f,0.f};
        #pragma unroll
        for (int kt=0;kt<4;++kt)
          acc = __builtin_amdgcn_mfma_f32_16x16x32_f16(af[kt], wb_[i][kt], acc, 0,0,0);
        const int col = ntl[i]*16 + l15;
        #pragma unroll
        for (int r=0;r<4;++r){
          int t = chunk*80 + mt*16 + lg*4 + r;
          float gv = acc[r] + bias[i] + ((t==tfirst)? m0w[i] : 0.f);
          Gh[((size_t)dir*51200 + (size_t)seq*400 + t)*400 + col] = h16(gv);
        }
      }
    }
    __syncthreads();
  }
}

// ---------- k_rec6: fused recurrence. gates (s,g)-quad + DPP exchange; proj lanes write out.
// 1 barrier/step, double-buffered h2. Loop t=0..TB: gates active t<TB, proj active t>=1 (m(t-1)).
__global__ __launch_bounds__(704, 1)
void k_rec6(const float* __restrict__ c0f, const float* __restrict__ c0b,
            const float* __restrict__ Pf, const float* __restrict__ Pb,
            const u32* __restrict__ Qp, const u16* __restrict__ Gh,
            float* __restrict__ out)
{
  __shared__ __align__(16) u32 h2[2][52];   // h f16-pairs; slots 50,51 = pad 0 (both parities)
  const int tid = threadIdx.x, dir = blockIdx.x>>7, seq = blockIdx.x&127;
  const float* c0 = dir?c0b:c0f;
  const float* P  = dir?Pb:Pf;
  const int s = tid>>2, g = tid&3;          // gates: cell s on quad, gate g (0:i 1:j 2:f 3:o)
  const int c = g*100 + s;

  uint4 wq[13];                             // gates Q column (52 u32, arch-VGPR resident)
  float cs = 0.f;
  if (tid < 400){
    #pragma unroll
    for (int q=0;q<13;++q){
      wq[q].x = Qp[(size_t)(dir*52+4*q+0)*400 + c];
      wq[q].y = Qp[(size_t)(dir*52+4*q+1)*400 + c];
      wq[q].z = Qp[(size_t)(dir*52+4*q+2)*400 + c];
      wq[q].w = Qp[(size_t)(dir*52+4*q+3)*400 + c];
    }
    cs = c0[(size_t)seq*100 + s];
  }
  const int pc = tid - 448;                 // proj: column pc in [0,200)
  uint4 pw[13];
  if (pc >= 0 && pc < 200){
    #pragma unroll
    for (int q=0;q<13;++q){
      u32 r[4];
      #pragma unroll
      for (int u=0;u<4;++u){
        int j = 4*q+u;
        r[u] = (j<50)? pk2(P[(size_t)(2*j)*200+pc], P[(size_t)(2*j+1)*200+pc]) : 0u;
      }
      pw[q] = make_uint4(r[0],r[1],r[2],r[3]);
    }
  }
  if (tid < 104) ((u32*)h2)[tid] = 0u;      // h(-1)=0; pads permanent
  __syncthreads();

  const u16* gptr = Gh + ((size_t)dir*51200 + (size_t)seq*400 + (dir?(TB-1):0))*400 + c;
  const intptr_t gstep = dir ? -400 : 400;
  u16 gn = 0;
  if (tid<400) gn = *gptr;

  for (int t=0; t<=TB; ++t){
    const int p = t&1;                      // h2[p] = h(t-1)
    if (tid < 400 && t < TB){
      u16 gc = gn;
      gptr += gstep;
      if (t+1 < TB) gn = *gptr;
      float a0=0.f,a1=0.f,a2=0.f,a3=0.f;
      #pragma unroll
      for (int q=0;q<13;++q){
        uint4 hv = *(const uint4*)(&h2[p][4*q]);
        a0=dot2f(wq[q].x,hv.x,a0); a1=dot2f(wq[q].y,hv.y,a1);
        a2=dot2f(wq[q].z,hv.z,a2); a3=dot2f(wq[q].w,hv.w,a3);
      }
      float a = ((a0+a1)+(a2+a3)) + f16f(gc);
      float arg = (g==1) ? a+a : a;         // tanh(x)=2*sig(2x)-1
      float v = sigf(arg);
      float act = (g==1) ? 2.0f*v-1.0f : v;
      float bx = qxor1(act);                // gate g^1
      float dx = qxor2(act);                // gate g^2
      float ex = qxor2(bx);                 // gate g^3
      float I = (g==0)?act:(g==1)?bx:(g==2)?dx:ex;
      float J = (g==1)?act:(g==0)?bx:(g==3)?dx:ex;
      float F = (g==2)?act:(g==3)?bx:(g==0)?dx:ex;
      float O = (g==3)?act:(g==2)?bx:(g==1)?dx:ex;
      float cc = F*cs + I*J; cs = cc;       // redundant x4, deterministic
      float h = O*tanhf_(cc);
      if (g==0) ((u16*)&h2[p^1][0])[s] = h16(h);
    } else if (pc >= 0 && pc < 200 && t >= 1){
      float m0=0.f,m1=0.f,m2=0.f,m3=0.f;
      #pragma unroll
      for (int q=0;q<13;++q){
        uint4 hv = *(const uint4*)(&h2[p][4*q]);
        m0=dot2f(pw[q].x,hv.x,m0); m1=dot2f(pw[q].y,hv.y,m1);
        m2=dot2f(pw[q].z,hv.z,m2); m3=dot2f(pw[q].w,hv.w,m3);
      }
      const int tt = dir ? (TB-t) : (t-1);  // orig time of step t-1
      __builtin_nontemporal_store((m0+m1)+(m2+m3),
          out + (size_t)seq*OUTROW + (size_t)tt*400 + dir*200 + pc);
    }
    __syncthreads();
  }
}

extern "C" void kernel_launch(void* const* d_in, const int* in_sizes, int n_in,
                              void* d_out, int out_size, void* d_ws, size_t ws_size,
                              hipStream_t stream) {
  (void)in_sizes; (void)n_in; (void)out_size; (void)ws_size;
  const float* z   = (const float*)d_in[0];
  const float* c0f = (const float*)d_in[1];
  const float* m0f = (const float*)d_in[2];
  const float* c0b = (const float*)d_in[3];
  const float* m0b = (const float*)d_in[4];
  const float* Wf  = (const float*)d_in[5];
  const float* bf  = (const float*)d_in[6];
  const float* Pf  = (const float*)d_in[7];
  const float* Wb  = (const float*)d_in[8];
  const float* bb  = (const float*)d_in[9];
  const float* Pb  = (const float*)d_in[10];

  u32*   Qp  = (u32*)d_ws;                            // 166,400 B
  float* M0W = (float*)((char*)d_ws + 196608);        // 409,600 B
  u16*   Gh  = (u16*)((char*)d_ws + 655360);          // 81,920,000 B (total ~82.6 MB)

  k_prep<<<360, 512, 0, stream>>>(Wf, Pf, Wb, Pb, m0f, m0b, Qp, M0W);
  k_g4  <<<256, 512, 0, stream>>>(z, Wf, bf, Wb, bb, M0W, Gh);
  k_rec6<<<256, 704, 0, stream>>>(c0f, c0b, Pf, Pb, Qp, Gh, (float*)d_out);
}